// Round 4
// baseline (244.947 us; speedup 1.0000x reference)
//
#include <hip/hip_runtime.h>

// Propagation: E = softsign(V V^T / sqrt(D)); out0 = E @ state; out1 = E @ V
// B=4, N=4096, D=256, fp32 in/out.
//
// Round 10 (from R9 @ 152us total / 86us prop_main):
//  - R9 post-mortem: 2 barrier domains helped (+11%) but occupancy stuck at
//    8 waves/CU -- LDS (75.7KB/block, vj dbuf = 64KB of it) caps blocks/CU=2.
//    MfmaUtil 34% vs 2483cy MFMA floor in a 6450cy iter.
//  - Fix: kill the vj LDS pipeline entirely. Prepass emits a SECOND
//    fragment-ordered array VG1[jb16][ks][l16][quad][8] (elem =
//    V[jb*16+l16][ks*32+quad*8+e]); GEMM1-B and the A-frag hoist read it as
//    dense 1KB/wave L2-direct loads (same trick R8 proved for GEMM2-B/VF).
//  - LDS/block: Esh dbuf 18.4KB + dsred = 18.9KB. ONE barrier/iter (Esh
//    write->read; WAR separated by next iter's barrier). launch_bounds
//    (256,3) -> 12 waves/CU, 3 independent barrier domains.
//  - G1-B dup (waves 0/2, 1/3 share c0) absorbed by L1. All feeds XCD-pinned
//    (x%8 = b*2+jh): per-XCD set ~3MB < 4MB L2. state read direct from L2.
//  - softsign folded: e = s/(16+|s|)  (== (s/16)/(1+|s/16|)).
//  - fallback: round-1 fused kernel if ws too small.

#define B_  4
#define N_  4096
#define D_  256

typedef __attribute__((ext_vector_type(8))) short short8;
typedef __attribute__((ext_vector_type(4))) float floatx4;

__device__ __forceinline__ unsigned short f2bf(float f) {
    unsigned int u = __float_as_uint(f);
    u += 0x7fff + ((u >> 16) & 1);   // RTNE
    return (unsigned short)(u >> 16);
}

// ---------------- pre-pass: fp32 -> bf16 VG1 (GEMM1/A frag order) + VF (GEMM2-B frag order) ----------------
// VG1 per batch: elem V[j][d] at offset ((j>>4)*8 + (d>>5))*512 + (j&15)*32 + (d&31).
//   Wave-load for (jb16, ks): lane(quad,l16) reads off l16*32 + quad*8 -> dense 1KB.
// VF per batch: [jb32][d][e32], elem = V[jb*32+e][d]; lane(quad,l16) reads
//   VF[jb][dbase+l16][quad*8..+8] -> dense 1KB.
__global__ __launch_bounds__(256)
void prepass_kernel(const float* __restrict__ val,
                    unsigned short* __restrict__ VG1,
                    unsigned short* __restrict__ VF) {
    __shared__ unsigned short tile[64][68];
    const int t   = threadIdx.x;
    const int blk = blockIdx.x;            // b*256 + it*4 + dt
    const int b   = blk >> 8;
    const int it  = (blk >> 2) & 63;
    const int dt  = blk & 3;
    const int i0  = it * 64, d0 = dt * 64;
    const float*    vb   = val + (size_t)b * N_ * D_;
    unsigned short* VG1b = VG1 + (size_t)b * N_ * D_;
    unsigned short* VFb  = VF  + (size_t)b * N_ * D_;

    #pragma unroll
    for (int q = 0; q < 4; ++q) {
        int idx = t + 256 * q;
        int row = idx >> 4;
        int c4  = idx & 15;
        const int j = i0 + row;
        const int d = d0 + c4 * 4;
        float4 v = *(const float4*)(vb + (size_t)j * D_ + d);
        ushort4 h;
        h.x = f2bf(v.x); h.y = f2bf(v.y); h.z = f2bf(v.z); h.w = f2bf(v.w);
        const size_t off = ((size_t)(j >> 4) * 8 + (d >> 5)) * 512
                         + (j & 15) * 32 + (d & 31);
        *(ushort4*)(VG1b + off) = h;
        *(ushort4*)&tile[row][c4 * 4] = h;
    }
    __syncthreads();
    #pragma unroll
    for (int q = 0; q < 4; ++q) {
        int dr = (t >> 4) + q * 16;     // d within tile
        int i4 = t & 15;                 // j-quad within 64
        ushort4 h;
        h.x = tile[i4 * 4 + 0][dr];
        h.y = tile[i4 * 4 + 1][dr];
        h.z = tile[i4 * 4 + 2][dr];
        h.w = tile[i4 * 4 + 3][dr];
        const int jb = (i0 >> 5) + (i4 >> 3);
        const int e  = (i4 & 7) * 4;
        *(ushort4*)(VFb + ((size_t)jb * 256 + d0 + dr) * 32 + e) = h;
    }
}

// ---------------- main fused kernel ----------------
// grid 512; XCD-pinned decode: it = x>>3 (0..63), b = (x>>1)&3, jh = x&1.
// 256 threads = 4 waves; block covers 64 i-rows x 2048 j (one jh half).
// All matrix feeds are L2-direct fragment-ordered loads; LDS only for Esh.
// 3 blocks/CU (launch_bounds (256,3)) -> 12 waves/CU, 3 barrier domains.
// LDS map (bytes), total 18944:
//   Esh  : 0 + buf*9216   (2 x 9216)   64 x 72 bf16, double-buffered
//   dsred: 18432          [2][64] f32
__global__ __launch_bounds__(256, 3)
void prop_main(const float* __restrict__ state,
               const unsigned short* __restrict__ VG1,
               const unsigned short* __restrict__ VF,
               float* __restrict__ dvp,   // [2][B][N][D] partials
               float* __restrict__ dsp_o) // [2][B][N]    partials
{
    __shared__ __attribute__((aligned(16))) unsigned char smem[18944];

    const int t    = threadIdx.x;
    const int w    = t >> 6;          // wave 0..3
    const int lane = t & 63;
    const int quad = lane >> 4;
    const int l16  = lane & 15;

    const int x   = blockIdx.x;
    const int it  = x >> 3;           // XCD pin: x%8 == b*2+jh
    const int b   = (x >> 1) & 3;
    const int jh  = x & 1;
    const int it0 = it * 64;
    const int jbase = jh * 2048;
    const int niter = 32;

    float* dsred = (float*)(smem + 18432);

    const unsigned short* VG1b = VG1 + (size_t)b * N_ * D_;
    const unsigned short* VFb  = VF  + (size_t)b * N_ * D_;
    const float*          stb  = state + (size_t)b * N_;

    const int r0 = (w >> 1) * 32;     // GEMM1 row base
    const int c0 = (w & 1) * 32;      // GEMM1 col (j) base

    // ---- hoist GEMM1 A-fragments to registers (loop-invariant) ----
    // A-frag (i=it0+r0+l16, d=ks*32+quad*8) lives at VG1 block (i>>4, ks),
    // lane offset l16*32+quad*8 -> dense 1KB wave-loads.
    short8 A0[8], A1[8];
    {
        const unsigned short* a0p = VG1b + (size_t)((it0 + r0) >> 4) * 4096
                                  + l16 * 32 + quad * 8;
        #pragma unroll
        for (int ks = 0; ks < 8; ++ks) {
            A0[ks] = *(const short8*)(a0p + ks * 512);
            A1[ks] = *(const short8*)(a0p + 4096 + ks * 512);
        }
    }

    // GEMM1 B base: j-rows [jbase+c0, +16) = VG1 block ((jbase+c0)>>4);
    // per k advance 4 jb16 blocks = 16384 elems; b1 (+16 j) = +4096.
    const unsigned short* g1p = VG1b + (size_t)((jbase + c0) >> 4) * 4096
                              + l16 * 32 + quad * 8;

    // GEMM2 B base in VF: addr(k,ks,c2) = vfp + k*16384 + ks*8192 + c2*512.
    const unsigned short* vfp = VFb + (size_t)(jbase >> 5) * 8192
                              + (w * 64 + l16) * 32 + quad * 8;

    floatx4 dv[4][4];
    #pragma unroll
    for (int a = 0; a < 4; ++a)
        #pragma unroll
        for (int c = 0; c < 4; ++c)
            dv[a][c] = (floatx4){0.f, 0.f, 0.f, 0.f};
    float dsp[8];
    #pragma unroll
    for (int k = 0; k < 8; ++k) dsp[k] = 0.f;

    for (int k = 0; k < niter; ++k) {
        const int buf = k & 1;
        unsigned short* Eshg = (unsigned short*)(smem + buf * 9216);
        const int j0 = jbase + k * 64;

        // state for this j-tile (L1/L2 direct; 16 distinct floats per wave)
        float stc0 = stb[j0 + c0 + l16];
        float stc1 = stb[j0 + c0 + 16 + l16];

        // ---- GEMM1: S = Vi . Vj^T (A regs, B = dense L2-direct loads) ----
        floatx4 sa[2][2];
        #pragma unroll
        for (int a = 0; a < 2; ++a)
            #pragma unroll
            for (int c = 0; c < 2; ++c)
                sa[a][c] = (floatx4){0.f, 0.f, 0.f, 0.f};

        const unsigned short* g1k = g1p + (size_t)k * 16384;
        #pragma unroll
        for (int ks = 0; ks < 8; ++ks) {
            short8 b0 = *(const short8*)(g1k + ks * 512);
            short8 b1 = *(const short8*)(g1k + 4096 + ks * 512);
            sa[0][0] = __builtin_amdgcn_mfma_f32_16x16x32_bf16(A0[ks], b0, sa[0][0], 0, 0, 0);
            sa[0][1] = __builtin_amdgcn_mfma_f32_16x16x32_bf16(A0[ks], b1, sa[0][1], 0, 0, 0);
            sa[1][0] = __builtin_amdgcn_mfma_f32_16x16x32_bf16(A1[ks], b0, sa[1][0], 0, 0, 0);
            sa[1][1] = __builtin_amdgcn_mfma_f32_16x16x32_bf16(A1[ks], b1, sa[1][1], 0, 0, 0);
        }

        // ---- GEMM2 B-frags: issued here, consumed after the barrier ----
        short8 bfr[2][4];
        {
            const unsigned short* vfk = vfp + (size_t)k * 16384;
            #pragma unroll
            for (int ks = 0; ks < 2; ++ks)
                #pragma unroll
                for (int c2 = 0; c2 < 4; ++c2)
                    bfr[ks][c2] = *(const short8*)(vfk + ks * 8192 + c2 * 512);
        }

        // ---- softsign epilogue: e = s/(16+|s|) -> Esh[buf] + ds partials ----
        #pragma unroll
        for (int a = 0; a < 2; ++a) {
            #pragma unroll
            for (int r = 0; r < 4; ++r) {
                const int il = r0 + a * 16 + quad * 4 + r;
                float s0 = sa[a][0][r];
                float s1 = sa[a][1][r];
                float e0 = s0 * __builtin_amdgcn_rcpf(16.0f + fabsf(s0));
                float e1 = s1 * __builtin_amdgcn_rcpf(16.0f + fabsf(s1));
                dsp[a * 4 + r] += e0 * stc0 + e1 * stc1;
                Eshg[il * 72 + c0 + l16]      = f2bf(e0);
                Eshg[il * 72 + c0 + 16 + l16] = f2bf(e1);
            }
        }
        __syncthreads();   // Esh[buf] visible (also drains bfr loads).
                           // WAR on Esh[buf] vs epilogue(k+2) is separated by
                           // the k+1 barrier -> double buffer is sufficient.

        // ---- GEMM2: dval += E . Vj (A from Esh[buf], B from regs) ----
        #pragma unroll
        for (int ks = 0; ks < 2; ++ks) {
            short8 af[4];
            #pragma unroll
            for (int a2 = 0; a2 < 4; ++a2)
                af[a2] = *(const short8*)&Eshg[(a2 * 16 + l16) * 72 + ks * 32 + quad * 8];
            #pragma unroll
            for (int a2 = 0; a2 < 4; ++a2)
                #pragma unroll
                for (int c2 = 0; c2 < 4; ++c2)
                    dv[a2][c2] = __builtin_amdgcn_mfma_f32_16x16x32_bf16(af[a2], bfr[ks][c2], dv[a2][c2], 0, 0, 0);
        }
    }

    // ---- epilogue: partial delta_val for this (i-tile, j-half) ----
    float* dvo = dvp + (size_t)jh * B_ * N_ * D_ + (size_t)b * N_ * D_
                     + (size_t)it0 * D_;
    #pragma unroll
    for (int a2 = 0; a2 < 4; ++a2)
        #pragma unroll
        for (int c2 = 0; c2 < 4; ++c2)
            #pragma unroll
            for (int r = 0; r < 4; ++r) {
                const int il = a2 * 16 + quad * 4 + r;
                const int d  = w * 64 + c2 * 16 + l16;
                dvo[(size_t)il * D_ + d] = dv[a2][c2][r];
            }

    // ---- epilogue: partial delta_state ----
    #pragma unroll
    for (int k = 0; k < 8; ++k) {
        float v = dsp[k];
        v += __shfl_xor(v, 1);
        v += __shfl_xor(v, 2);
        v += __shfl_xor(v, 4);
        v += __shfl_xor(v, 8);
        dsp[k] = v;
    }
    if (l16 == 0) {
        #pragma unroll
        for (int a = 0; a < 2; ++a)
            #pragma unroll
            for (int r = 0; r < 4; ++r) {
                const int row = r0 + a * 16 + quad * 4 + r;
                dsred[(w & 1) * 64 + row] = dsp[a * 4 + r];
            }
    }
    __syncthreads();
    if (t < 64)
        dsp_o[(size_t)jh * B_ * N_ + (size_t)b * N_ + it0 + t]
            = dsred[t] + dsred[64 + t];
}

// ---------------- combine: out = sum of the two j-half partials ----------------
__global__ __launch_bounds__(256)
void combine_kernel(const float4* __restrict__ dv0, const float4* __restrict__ dv1,
                    const float*  __restrict__ ds0, const float*  __restrict__ ds1,
                    float* __restrict__ out) {
    const int NDV4 = B_ * N_ * D_ / 4;   // 1048576
    const int NDS  = B_ * N_;            // 16384
    int x = blockIdx.x * 256 + threadIdx.x;
    if (x < NDV4) {
        float4 a = dv0[x], c = dv1[x];
        float4 r;
        r.x = a.x + c.x; r.y = a.y + c.y; r.z = a.z + c.z; r.w = a.w + c.w;
        ((float4*)(out + NDS))[x] = r;
    } else {
        int y = (x - NDV4) * 4;
        if (y < NDS) {
            float4 a = *(const float4*)(ds0 + y);
            float4 c = *(const float4*)(ds1 + y);
            float4 r;
            r.x = a.x + c.x; r.y = a.y + c.y; r.z = a.z + c.z; r.w = a.w + c.w;
            *(float4*)(out + y) = r;
        }
    }
}

// ---------------- fallback (round-1 kernel, used if ws too small) ----------------
__global__ __launch_bounds__(256, 1)
void prop_kernel_fb(const float* __restrict__ val,
                    const float* __restrict__ state,
                    float* __restrict__ out) {
    __shared__ __attribute__((aligned(16))) unsigned short vi[64][264];
    __shared__ __attribute__((aligned(16))) unsigned short vj[64][264];
    __shared__ __attribute__((aligned(16))) unsigned short vjt[2048][8];
    __shared__ __attribute__((aligned(16))) unsigned short Esh[64][72];
    __shared__ float stj[64];
    __shared__ float dsred[2][64];

    const int t    = threadIdx.x;
    const int w    = t >> 6;
    const int lane = t & 63;
    const int quad = lane >> 4;
    const int l16  = lane & 15;
    const int b   = blockIdx.x >> 6;
    const int it0 = (blockIdx.x & 63) << 6;
    const float* valb = val   + (size_t)b * N_ * D_;
    const float* stb  = state + (size_t)b * N_;

    #pragma unroll
    for (int n = 0; n < 16; ++n) {
        int idx = t + 256 * n;
        int row = idx >> 6;
        int c4  = idx & 63;
        float4 v = *(const float4*)(valb + (size_t)(it0 + row) * D_ + c4 * 4);
        ushort4 h;
        h.x = f2bf(v.x); h.y = f2bf(v.y); h.z = f2bf(v.z); h.w = f2bf(v.w);
        *(ushort4*)&vi[row][c4 * 4] = h;
    }

    const int r0 = (w >> 1) * 32;
    const int c0 = (w & 1) * 32;
    floatx4 dv[4][4];
    #pragma unroll
    for (int a = 0; a < 4; ++a)
        #pragma unroll
        for (int c = 0; c < 4; ++c)
            dv[a][c] = (floatx4){0.f, 0.f, 0.f, 0.f};
    float dsp[8];
    #pragma unroll
    for (int k = 0; k < 8; ++k) dsp[k] = 0.f;

    for (int jt = 0; jt < 64; ++jt) {
        const int j0 = jt * 64;
        #pragma unroll
        for (int n = 0; n < 16; ++n) {
            int idx = t + 256 * n;
            int row = idx >> 6;
            int c4  = idx & 63;
            float4 v = *(const float4*)(valb + (size_t)(j0 + row) * D_ + c4 * 4);
            ushort4 h;
            h.x = f2bf(v.x); h.y = f2bf(v.y); h.z = f2bf(v.z); h.w = f2bf(v.w);
            *(ushort4*)&vj[row][c4 * 4] = h;
        }
        if (t < 64) stj[t] = stb[j0 + t];
        __syncthreads();

        #pragma unroll
        for (int n = 0; n < 8; ++n) {
            const int d  = t;
            const int jb = n;
            short8 pk;
            #pragma unroll
            for (int jj = 0; jj < 8; ++jj) pk[jj] = (short)vj[jb * 8 + jj][d];
            *(short8*)&vjt[d * 8 + (jb ^ (d & 7))][0] = pk;
        }

        floatx4 sa[2][2];
        #pragma unroll
        for (int a = 0; a < 2; ++a)
            #pragma unroll
            for (int c = 0; c < 2; ++c)
                sa[a][c] = (floatx4){0.f, 0.f, 0.f, 0.f};
        #pragma unroll
        for (int ks = 0; ks < 8; ++ks) {
            const int d0 = ks * 32 + quad * 8;
            short8 a0 = *(const short8*)&vi[r0 + l16][d0];
            short8 a1 = *(const short8*)&vi[r0 + 16 + l16][d0];
            short8 b0 = *(const short8*)&vj[c0 + l16][d0];
            short8 b1 = *(const short8*)&vj[c0 + 16 + l16][d0];
            sa[0][0] = __builtin_amdgcn_mfma_f32_16x16x32_bf16(a0, b0, sa[0][0], 0, 0, 0);
            sa[0][1] = __builtin_amdgcn_mfma_f32_16x16x32_bf16(a0, b1, sa[0][1], 0, 0, 0);
            sa[1][0] = __builtin_amdgcn_mfma_f32_16x16x32_bf16(a1, b0, sa[1][0], 0, 0, 0);
            sa[1][1] = __builtin_amdgcn_mfma_f32_16x16x32_bf16(a1, b1, sa[1][1], 0, 0, 0);
        }

        float stc0 = stj[c0 + l16];
        float stc1 = stj[c0 + 16 + l16];
        #pragma unroll
        for (int a = 0; a < 2; ++a) {
            #pragma unroll
            for (int r = 0; r < 4; ++r) {
                const int il = r0 + a * 16 + quad * 4 + r;
                float s0 = sa[a][0][r] * 0.0625f;
                float s1 = sa[a][1][r] * 0.0625f;
                float e0 = s0 / (1.0f + fabsf(s0));
                float e1 = s1 / (1.0f + fabsf(s1));
                dsp[a * 4 + r] += e0 * stc0 + e1 * stc1;
                Esh[il][c0 + l16]      = f2bf(e0);
                Esh[il][c0 + 16 + l16] = f2bf(e1);
            }
        }
        __syncthreads();

        #pragma unroll
        for (int ks = 0; ks < 2; ++ks) {
            short8 af[4], bfr[4];
            #pragma unroll
            for (int a2 = 0; a2 < 4; ++a2)
                af[a2] = *(const short8*)&Esh[a2 * 16 + l16][ks * 32 + quad * 8];
            #pragma unroll
            for (int c2 = 0; c2 < 4; ++c2) {
                const int d  = w * 64 + c2 * 16 + l16;
                const int jb = ks * 4 + quad;
                bfr[c2] = *(const short8*)&vjt[d * 8 + (jb ^ (d & 7))][0];
            }
            #pragma unroll
            for (int a2 = 0; a2 < 4; ++a2)
                #pragma unroll
                for (int c2 = 0; c2 < 4; ++c2)
                    dv[a2][c2] = __builtin_amdgcn_mfma_f32_16x16x32_bf16(af[a2], bfr[c2], dv[a2][c2], 0, 0, 0);
        }
    }

    float* dvo = out + (size_t)B_ * N_ + (size_t)b * N_ * D_;
    #pragma unroll
    for (int a2 = 0; a2 < 4; ++a2)
        #pragma unroll
        for (int c2 = 0; c2 < 4; ++c2)
            #pragma unroll
            for (int r = 0; r < 4; ++r) {
                const int i = it0 + a2 * 16 + quad * 4 + r;
                const int d = w * 64 + c2 * 16 + l16;
                dvo[(size_t)i * D_ + d] = dv[a2][c2][r];
            }

    #pragma unroll
    for (int k = 0; k < 8; ++k) {
        float v = dsp[k];
        v += __shfl_xor(v, 1);
        v += __shfl_xor(v, 2);
        v += __shfl_xor(v, 4);
        v += __shfl_xor(v, 8);
        dsp[k] = v;
    }
    if (l16 == 0) {
        #pragma unroll
        for (int a = 0; a < 2; ++a)
            #pragma unroll
            for (int r = 0; r < 4; ++r) {
                const int row = (w >> 1) * 32 + a * 16 + quad * 4 + r;
                dsred[w & 1][row] = dsp[a * 4 + r];
            }
    }
    __syncthreads();
    if (t < 64) out[(size_t)b * N_ + it0 + t] = dsred[0][t] + dsred[1][t];
}

extern "C" void kernel_launch(void* const* d_in, const int* in_sizes, int n_in,
                              void* d_out, int out_size, void* d_ws, size_t ws_size,
                              hipStream_t stream) {
    const float* val   = (const float*)d_in[0];
    const float* state = (const float*)d_in[1];
    float* out = (float*)d_out;

    const size_t nE         = (size_t)B_ * N_ * D_;                 // 4,194,304
    const size_t need_base  = 2 * nE * sizeof(unsigned short);      // 16.78 MB
    const size_t need_split = need_base + 2 * nE * sizeof(float)
                            + 2 * (size_t)B_ * N_ * sizeof(float);  // ~50.5 MB

    if (ws_size >= need_split) {
        unsigned short* VG1 = (unsigned short*)d_ws;
        unsigned short* VF  = VG1 + nE;
        float* dvp = (float*)(VF + nE);          // [2][B*N*D]
        float* dsp = dvp + 2 * nE;               // [2][B*N]
        prepass_kernel<<<dim3(1024), dim3(256), 0, stream>>>(val, VG1, VF);
        prop_main<<<dim3(512), dim3(256), 0, stream>>>(state, VG1, VF, dvp, dsp);
        const int NDV4 = B_ * N_ * D_ / 4;
        const int NDS4 = B_ * N_ / 4;
        combine_kernel<<<dim3((NDV4 + NDS4) / 256), dim3(256), 0, stream>>>(
            (const float4*)dvp, (const float4*)(dvp + nE),
            dsp, dsp + (size_t)B_ * N_, out);
    } else {
        prop_kernel_fb<<<dim3(256), dim3(256), 0, stream>>>(val, state, out);
    }
}

// Round 6
// 153.538 us; speedup vs baseline: 1.5953x; 1.5953x over previous
//
#include <hip/hip_runtime.h>

// Propagation: E = softsign(V V^T / sqrt(D)); out0 = E @ state; out1 = E @ V
// B=4, N=4096, D=256, fp32 in/out.
//
// Round 12 == Round 11 resubmit (R11 bench was an infra failure: container
// died twice before pytest; no kernel signal). One hardening: "memory"
// clobber on the B2 inline waitcnt.
//
// Round 11 (revert R10; base = R9 @ 86us prop_main):
//  - R10 post-mortem: all-global feeds overran L2 (~300 B/cyc/CU demand vs
//    ~56 ceiling) -> 180us. vj LDS staging is load-bearing (BW amplification).
//  - Change A (T3/T4): bfr loads issued BEFORE stage(k+1) DMAs (bfr = oldest),
//    and B2 = raw s_barrier + lgkmcnt(0) only. Compiler then emits a COUNTED
//    vmcnt(~9) before GEMM2 (bfr done, stage DMAs stay in flight across the
//    barrier; they drain at B1(k+1) with a full-iteration window). R9's
//    __syncthreads B2 forced vmcnt(0) = the serialization stall.
//  - Change B (T2): Esh XOR-swizzle [64][64] (col-block (c>>3)^(il&7), no
//    pad). Old stride-72 layout was an 8-way bank conflict on the af
//    ds_read_b128 (bank-step 4/row) = the 6.29M SQ_LDS_BANK_CONFLICT.
//  - Keep: vj dbuf staged at top (gl_lds16), VF L2-direct GEMM2-B, XCD pin
//    (x%8 = b*2+jh), Esh single-buffered, 2 blocks/CU, launch_bounds(256,2).
//  - softsign folded: e = s/(16+|s|)  (== (s/16)/(1+|s/16|)).
//  - fallback: round-1 fused kernel if ws too small.

#define B_  4
#define N_  4096
#define D_  256

typedef __attribute__((ext_vector_type(8))) short short8;
typedef __attribute__((ext_vector_type(4))) float floatx4;

__device__ __forceinline__ unsigned short f2bf(float f) {
    unsigned int u = __float_as_uint(f);
    u += 0x7fff + ((u >> 16) & 1);   // RTNE
    return (unsigned short)(u >> 16);
}

__device__ __forceinline__ void gl_lds16(const void* g, void* l) {
    __builtin_amdgcn_global_load_lds(
        (const __attribute__((address_space(1))) unsigned int*)g,
        (__attribute__((address_space(3))) unsigned int*)l, 16, 0, 0);
}
__device__ __forceinline__ void gl_lds4(const void* g, void* l) {
    __builtin_amdgcn_global_load_lds(
        (const __attribute__((address_space(1))) unsigned int*)g,
        (__attribute__((address_space(3))) unsigned int*)l, 4, 0, 0);
}

// ---------------- pre-pass: fp32 -> bf16 Vb (row-major) + fragment-ordered VF ----------------
// VF layout per batch: [jb 0..127][d 0..255][e 0..31], elem = V[jb*32+e][d].
// GEMM2 B-frag load is contiguous: lane(quad,l16) reads
// VF[jb][dbase+l16][quad*8..+8] -> offsets l16*64B + quad*16B (dense 1KB/wave).
__global__ __launch_bounds__(256)
void prepass_kernel(const float* __restrict__ val,
                    unsigned short* __restrict__ Vb,
                    unsigned short* __restrict__ VF) {
    __shared__ unsigned short tile[64][68];
    const int t   = threadIdx.x;
    const int blk = blockIdx.x;            // b*256 + it*4 + dt
    const int b   = blk >> 8;
    const int it  = (blk >> 2) & 63;
    const int dt  = blk & 3;
    const int i0  = it * 64, d0 = dt * 64;
    const float*    vb  = val + (size_t)b * N_ * D_;
    unsigned short* Vbb = Vb  + (size_t)b * N_ * D_;
    unsigned short* VFb = VF  + (size_t)b * N_ * D_;

    #pragma unroll
    for (int q = 0; q < 4; ++q) {
        int idx = t + 256 * q;
        int row = idx >> 4;
        int c4  = idx & 15;
        float4 v = *(const float4*)(vb + (size_t)(i0 + row) * D_ + d0 + c4 * 4);
        ushort4 h;
        h.x = f2bf(v.x); h.y = f2bf(v.y); h.z = f2bf(v.z); h.w = f2bf(v.w);
        *(ushort4*)(Vbb + (size_t)(i0 + row) * D_ + d0 + c4 * 4) = h;
        *(ushort4*)&tile[row][c4 * 4] = h;
    }
    __syncthreads();
    #pragma unroll
    for (int q = 0; q < 4; ++q) {
        int dr = (t >> 4) + q * 16;     // d within tile
        int i4 = t & 15;                 // j-quad within 64
        ushort4 h;
        h.x = tile[i4 * 4 + 0][dr];
        h.y = tile[i4 * 4 + 1][dr];
        h.z = tile[i4 * 4 + 2][dr];
        h.w = tile[i4 * 4 + 3][dr];
        const int jb = (i0 >> 5) + (i4 >> 3);
        const int e  = (i4 & 7) * 4;
        *(ushort4*)(VFb + ((size_t)jb * 256 + d0 + dr) * 32 + e) = h;
    }
}

// ---------------- main fused kernel ----------------
// grid 512; XCD-pinned decode: it = x>>3 (0..63), b = (x>>1)&3, jh = x&1.
// 256 threads = 4 waves; block covers 64 i-rows x 2048 j (one jh half).
// 2 blocks/CU (launch_bounds 256,2) -> 2 independent barrier domains.
// LDS map (bytes), total 74752:
//   vj   : 0     + buf*32768   (2 x 32768)  [64 j][256 d] granule-swizzled
//   Esh  : 65536               (8192)       [64][64] bf16, XOR-swizzled, single
//   stj  : 73728 + buf*256     (2 x 64 f32)
//   dsred: 74240               [2][64] f32
__global__ __launch_bounds__(256, 2)
void prop_main(const float* __restrict__ state,
               const unsigned short* __restrict__ Vb,
               const unsigned short* __restrict__ VF,
               float* __restrict__ dvp,   // [2][B][N][D] partials
               float* __restrict__ dsp_o) // [2][B][N]    partials
{
    __shared__ __attribute__((aligned(16))) unsigned char smem[74752];

    const int t    = threadIdx.x;
    const int w    = t >> 6;          // wave 0..3
    const int lane = t & 63;
    const int quad = lane >> 4;
    const int l16  = lane & 15;

    const int x   = blockIdx.x;
    const int it  = x >> 3;           // XCD pin: x%8 == b*2+jh
    const int b   = (x >> 1) & 3;
    const int jh  = x & 1;
    const int it0 = it * 64;
    const int jbase = jh * 2048;
    const int niter = 32;

    unsigned short* EshL = (unsigned short*)(smem + 65536);
    float*          dsred = (float*)(smem + 74240);

    const unsigned short* Vbb = Vb + (size_t)b * N_ * D_;
    const unsigned short* VFb = VF + (size_t)b * N_ * D_;
    const float*          stb = state + (size_t)b * N_;

    const int hi  = lane >> 5;
    const int p32 = lane & 31;

    // per-wave staging offsets for vj (4 waves cooperatively stage 64 rows)
    int vgoff[8];   // vj: rows 2*(w*8+n)+hi, granule-swizzled
    #pragma unroll
    for (int n = 0; n < 8; ++n) {
        int r  = 2 * (w * 8 + n) + hi;           // 0..63
        int gr = p32 ^ (r & 7);
        vgoff[n] = r * 256 + gr * 8;
    }

    const int r0 = (w >> 1) * 32;     // GEMM1 row base
    const int c0 = (w & 1) * 32;      // GEMM1 col (j) base
    const int pA = l16 & 7;
    const int cB = (w & 1) * 4 + (l16 >> 3);  // Esh col-block base for writes
    const int l7 = l16 & 7;

    // GEMM2 B-frag lane base in VF (contiguous 1KB per wave-load):
    // addr(k,ks,c2) = vf_lane + k*16384 + ks*8192 + c2*512   (elems)
    const unsigned short* vf_lane = VFb + (size_t)jh * (64 * 8192)
                                  + w * 2048 + l16 * 32 + quad * 8;

    // ---- hoist GEMM1 A-fragments to registers (loop-invariant) ----
    short8 A0[8], A1[8];
    {
        const unsigned short* ar0 = Vbb + (size_t)(it0 + r0 + l16) * 256 + quad * 8;
        const unsigned short* ar1 = ar0 + 16 * 256;
        #pragma unroll
        for (int ks = 0; ks < 8; ++ks) {
            A0[ks] = *(const short8*)(ar0 + ks * 32);
            A1[ks] = *(const short8*)(ar1 + ks * 32);
        }
    }

    // ---- prologue: stage tile 0 (vj -> buf0, stj -> buf0) ----
    #pragma unroll
    for (int n = 0; n < 8; ++n)
        gl_lds16(Vbb + (size_t)jbase * 256 + vgoff[n],
                 smem + (w * 8 + n) * 1024);
    if (w == 0) gl_lds4(stb + jbase + lane, smem + 73728);

    floatx4 dv[4][4];
    #pragma unroll
    for (int a = 0; a < 4; ++a)
        #pragma unroll
        for (int c = 0; c < 4; ++c)
            dv[a][c] = (floatx4){0.f, 0.f, 0.f, 0.f};
    float dsp[8];
    #pragma unroll
    for (int k = 0; k < 8; ++k) dsp[k] = 0.f;

    for (int k = 0; k < niter; ++k) {
        const int buf = k & 1;
        unsigned short* vjL = (unsigned short*)(smem + buf * 32768);
        const float*    stj = (const float*)(smem + 73728 + buf * 256);

        __syncthreads();   // B1: vj[buf](k), stj[buf](k) visible (drains the
                           // stage DMAs issued last iter -- full-iter window);
                           // also separates prev GEMM2's Esh reads (WAR).

        // ---- GEMM2 B-frags FIRST (oldest vmem ops) so the pre-GEMM2 wait
        //      can be a counted vmcnt leaving the stage DMAs in flight. ----
        short8 bfr[2][4];
        {
            const unsigned short* vfk = vf_lane + (size_t)k * 16384;
            #pragma unroll
            for (int ks = 0; ks < 2; ++ks)
                #pragma unroll
                for (int c2 = 0; c2 < 4; ++c2)
                    bfr[ks][c2] = *(const short8*)(vfk + ks * 8192 + c2 * 512);
        }
        __builtin_amdgcn_sched_barrier(0);   // pin: bfr issued before stage

        // ---- stage vj(k+1)/stj(k+1) into the other buffer ----
        if (k + 1 < niter) {
            const size_t j0n = jbase + (size_t)(k + 1) * 64;
            #pragma unroll
            for (int n = 0; n < 8; ++n)
                gl_lds16(Vbb + j0n * 256 + vgoff[n],
                         smem + (buf ^ 1) * 32768 + (w * 8 + n) * 1024);
            if (w == 0) gl_lds4(stb + j0n + lane, smem + 73728 + (buf ^ 1) * 256);
        }

        // ---- GEMM1: S = Vi . Vj^T (K=256, A from registers, B from vj) ----
        floatx4 sa[2][2];
        #pragma unroll
        for (int a = 0; a < 2; ++a)
            #pragma unroll
            for (int c = 0; c < 2; ++c)
                sa[a][c] = (floatx4){0.f, 0.f, 0.f, 0.f};

        #pragma unroll
        for (int ks = 0; ks < 8; ++ks) {
            const int p = ((ks * 4 + quad) ^ pA) * 8;
            short8 b0 = *(const short8*)&vjL[(c0 + l16) * 256 + p];
            short8 b1 = *(const short8*)&vjL[(c0 + 16 + l16) * 256 + p];
            sa[0][0] = __builtin_amdgcn_mfma_f32_16x16x32_bf16(A0[ks], b0, sa[0][0], 0, 0, 0);
            sa[0][1] = __builtin_amdgcn_mfma_f32_16x16x32_bf16(A0[ks], b1, sa[0][1], 0, 0, 0);
            sa[1][0] = __builtin_amdgcn_mfma_f32_16x16x32_bf16(A1[ks], b0, sa[1][0], 0, 0, 0);
            sa[1][1] = __builtin_amdgcn_mfma_f32_16x16x32_bf16(A1[ks], b1, sa[1][1], 0, 0, 0);
        }

        // ---- softsign epilogue: e = s/(16+|s|) -> Esh (XOR-swizzled) ----
        float stc0 = stj[c0 + l16];
        float stc1 = stj[c0 + 16 + l16];
        #pragma unroll
        for (int a = 0; a < 2; ++a) {
            #pragma unroll
            for (int r = 0; r < 4; ++r) {
                const int il  = r0 + a * 16 + quad * 4 + r;
                const int ilb = (quad * 4 + r) & 7;      // == il & 7
                float s0 = sa[a][0][r];
                float s1 = sa[a][1][r];
                float e0 = s0 * __builtin_amdgcn_rcpf(16.0f + fabsf(s0));
                float e1 = s1 * __builtin_amdgcn_rcpf(16.0f + fabsf(s1));
                dsp[a * 4 + r] += e0 * stc0 + e1 * stc1;
                EshL[il * 64 + ((cB ^ ilb) << 3) + l7]       = f2bf(e0);
                EshL[il * 64 + (((cB + 2) ^ ilb) << 3) + l7] = f2bf(e1);
            }
        }

        // ---- B2: raw barrier. lgkmcnt(0) drains the Esh ds_writes; NO
        //      vmcnt drain here -- compiler inserts a counted vmcnt before
        //      GEMM2's first bfr use (stage DMAs remain outstanding). ----
        __builtin_amdgcn_sched_barrier(0);
        asm volatile("s_waitcnt lgkmcnt(0)" ::: "memory");
        __builtin_amdgcn_s_barrier();
        __builtin_amdgcn_sched_barrier(0);

        // ---- GEMM2: dval += E . Vj (A from Esh, B from regs) ----
        #pragma unroll
        for (int ks = 0; ks < 2; ++ks) {
            short8 af[4];
            #pragma unroll
            for (int a2 = 0; a2 < 4; ++a2)
                af[a2] = *(const short8*)&EshL[(a2 * 16 + l16) * 64
                                               + (((ks * 4 + quad) ^ l7) << 3)];
            #pragma unroll
            for (int a2 = 0; a2 < 4; ++a2)
                #pragma unroll
                for (int c2 = 0; c2 < 4; ++c2)
                    dv[a2][c2] = __builtin_amdgcn_mfma_f32_16x16x32_bf16(af[a2], bfr[ks][c2], dv[a2][c2], 0, 0, 0);
        }
        // next barrier is B1 of iter k+1 (separates these Esh reads from the
        // next epilogue's Esh writes -> single Esh buffer is safe)
    }

    // ---- epilogue: partial delta_val for this (i-tile, j-half) ----
    float* dvo = dvp + (size_t)jh * B_ * N_ * D_ + (size_t)b * N_ * D_
                     + (size_t)it0 * D_;
    #pragma unroll
    for (int a2 = 0; a2 < 4; ++a2)
        #pragma unroll
        for (int c2 = 0; c2 < 4; ++c2)
            #pragma unroll
            for (int r = 0; r < 4; ++r) {
                const int il = a2 * 16 + quad * 4 + r;
                const int d  = w * 64 + c2 * 16 + l16;
                dvo[(size_t)il * D_ + d] = dv[a2][c2][r];
            }

    // ---- epilogue: partial delta_state ----
    #pragma unroll
    for (int k = 0; k < 8; ++k) {
        float v = dsp[k];
        v += __shfl_xor(v, 1);
        v += __shfl_xor(v, 2);
        v += __shfl_xor(v, 4);
        v += __shfl_xor(v, 8);
        dsp[k] = v;
    }
    if (l16 == 0) {
        #pragma unroll
        for (int a = 0; a < 2; ++a)
            #pragma unroll
            for (int r = 0; r < 4; ++r) {
                const int row = r0 + a * 16 + quad * 4 + r;
                dsred[(w & 1) * 64 + row] = dsp[a * 4 + r];
            }
    }
    __syncthreads();
    if (t < 64)
        dsp_o[(size_t)jh * B_ * N_ + (size_t)b * N_ + it0 + t]
            = dsred[t] + dsred[64 + t];
}

// ---------------- combine: out = sum of the two j-half partials ----------------
__global__ __launch_bounds__(256)
void combine_kernel(const float4* __restrict__ dv0, const float4* __restrict__ dv1,
                    const float*  __restrict__ ds0, const float*  __restrict__ ds1,
                    float* __restrict__ out) {
    const int NDV4 = B_ * N_ * D_ / 4;   // 1048576
    const int NDS  = B_ * N_;            // 16384
    int x = blockIdx.x * 256 + threadIdx.x;
    if (x < NDV4) {
        float4 a = dv0[x], c = dv1[x];
        float4 r;
        r.x = a.x + c.x; r.y = a.y + c.y; r.z = a.z + c.z; r.w = a.w + c.w;
        ((float4*)(out + NDS))[x] = r;
    } else {
        int y = (x - NDV4) * 4;
        if (y < NDS) {
            float4 a = *(const float4*)(ds0 + y);
            float4 c = *(const float4*)(ds1 + y);
            float4 r;
            r.x = a.x + c.x; r.y = a.y + c.y; r.z = a.z + c.z; r.w = a.w + c.w;
            *(float4*)(out + y) = r;
        }
    }
}

// ---------------- fallback (round-1 kernel, used if ws too small) ----------------
__global__ __launch_bounds__(256, 1)
void prop_kernel_fb(const float* __restrict__ val,
                    const float* __restrict__ state,
                    float* __restrict__ out) {
    __shared__ __attribute__((aligned(16))) unsigned short vi[64][264];
    __shared__ __attribute__((aligned(16))) unsigned short vj[64][264];
    __shared__ __attribute__((aligned(16))) unsigned short vjt[2048][8];
    __shared__ __attribute__((aligned(16))) unsigned short Esh[64][72];
    __shared__ float stj[64];
    __shared__ float dsred[2][64];

    const int t    = threadIdx.x;
    const int w    = t >> 6;
    const int lane = t & 63;
    const int quad = lane >> 4;
    const int l16  = lane & 15;
    const int b   = blockIdx.x >> 6;
    const int it0 = (blockIdx.x & 63) << 6;
    const float* valb = val   + (size_t)b * N_ * D_;
    const float* stb  = state + (size_t)b * N_;

    #pragma unroll
    for (int n = 0; n < 16; ++n) {
        int idx = t + 256 * n;
        int row = idx >> 6;
        int c4  = idx & 63;
        float4 v = *(const float4*)(valb + (size_t)(it0 + row) * D_ + c4 * 4);
        ushort4 h;
        h.x = f2bf(v.x); h.y = f2bf(v.y); h.z = f2bf(v.z); h.w = f2bf(v.w);
        *(ushort4*)&vi[row][c4 * 4] = h;
    }

    const int r0 = (w >> 1) * 32;
    const int c0 = (w & 1) * 32;
    floatx4 dv[4][4];
    #pragma unroll
    for (int a = 0; a < 4; ++a)
        #pragma unroll
        for (int c = 0; c < 4; ++c)
            dv[a][c] = (floatx4){0.f, 0.f, 0.f, 0.f};
    float dsp[8];
    #pragma unroll
    for (int k = 0; k < 8; ++k) dsp[k] = 0.f;

    for (int jt = 0; jt < 64; ++jt) {
        const int j0 = jt * 64;
        #pragma unroll
        for (int n = 0; n < 16; ++n) {
            int idx = t + 256 * n;
            int row = idx >> 6;
            int c4  = idx & 63;
            float4 v = *(const float4*)(valb + (size_t)(j0 + row) * D_ + c4 * 4);
            ushort4 h;
            h.x = f2bf(v.x); h.y = f2bf(v.y); h.z = f2bf(v.z); h.w = f2bf(v.w);
            *(ushort4*)&vj[row][c4 * 4] = h;
        }
        if (t < 64) stj[t] = stb[j0 + t];
        __syncthreads();

        #pragma unroll
        for (int n = 0; n < 8; ++n) {
            const int d  = t;
            const int jb = n;
            short8 pk;
            #pragma unroll
            for (int jj = 0; jj < 8; ++jj) pk[jj] = (short)vj[jb * 8 + jj][d];
            *(short8*)&vjt[d * 8 + (jb ^ (d & 7))][0] = pk;
        }

        floatx4 sa[2][2];
        #pragma unroll
        for (int a = 0; a < 2; ++a)
            #pragma unroll
            for (int c = 0; c < 2; ++c)
                sa[a][c] = (floatx4){0.f, 0.f, 0.f, 0.f};
        #pragma unroll
        for (int ks = 0; ks < 8; ++ks) {
            const int d0 = ks * 32 + quad * 8;
            short8 a0 = *(const short8*)&vi[r0 + l16][d0];
            short8 a1 = *(const short8*)&vi[r0 + 16 + l16][d0];
            short8 b0 = *(const short8*)&vj[c0 + l16][d0];
            short8 b1 = *(const short8*)&vj[c0 + 16 + l16][d0];
            sa[0][0] = __builtin_amdgcn_mfma_f32_16x16x32_bf16(a0, b0, sa[0][0], 0, 0, 0);
            sa[0][1] = __builtin_amdgcn_mfma_f32_16x16x32_bf16(a0, b1, sa[0][1], 0, 0, 0);
            sa[1][0] = __builtin_amdgcn_mfma_f32_16x16x32_bf16(a1, b0, sa[1][0], 0, 0, 0);
            sa[1][1] = __builtin_amdgcn_mfma_f32_16x16x32_bf16(a1, b1, sa[1][1], 0, 0, 0);
        }

        float stc0 = stj[c0 + l16];
        float stc1 = stj[c0 + 16 + l16];
        #pragma unroll
        for (int a = 0; a < 2; ++a) {
            #pragma unroll
            for (int r = 0; r < 4; ++r) {
                const int il = r0 + a * 16 + quad * 4 + r;
                float s0 = sa[a][0][r] * 0.0625f;
                float s1 = sa[a][1][r] * 0.0625f;
                float e0 = s0 / (1.0f + fabsf(s0));
                float e1 = s1 / (1.0f + fabsf(s1));
                dsp[a * 4 + r] += e0 * stc0 + e1 * stc1;
                Esh[il][c0 + l16]      = f2bf(e0);
                Esh[il][c0 + 16 + l16] = f2bf(e1);
            }
        }
        __syncthreads();

        #pragma unroll
        for (int ks = 0; ks < 2; ++ks) {
            short8 af[4], bfr[4];
            #pragma unroll
            for (int a2 = 0; a2 < 4; ++a2)
                af[a2] = *(const short8*)&Esh[a2 * 16 + l16][ks * 32 + quad * 8];
            #pragma unroll
            for (int c2 = 0; c2 < 4; ++c2) {
                const int d  = w * 64 + c2 * 16 + l16;
                const int jb = ks * 4 + quad;
                bfr[c2] = *(const short8*)&vjt[d * 8 + (jb ^ (d & 7))][0];
            }
            #pragma unroll
            for (int a2 = 0; a2 < 4; ++a2)
                #pragma unroll
                for (int c2 = 0; c2 < 4; ++c2)
                    dv[a2][c2] = __builtin_amdgcn_mfma_f32_16x16x32_bf16(af[a2], bfr[c2], dv[a2][c2], 0, 0, 0);
        }
    }

    float* dvo = out + (size_t)B_ * N_ + (size_t)b * N_ * D_;
    #pragma unroll
    for (int a2 = 0; a2 < 4; ++a2)
        #pragma unroll
        for (int c2 = 0; c2 < 4; ++c2)
            #pragma unroll
            for (int r = 0; r < 4; ++r) {
                const int i = it0 + a2 * 16 + quad * 4 + r;
                const int d = w * 64 + c2 * 16 + l16;
                dvo[(size_t)i * D_ + d] = dv[a2][c2][r];
            }

    #pragma unroll
    for (int k = 0; k < 8; ++k) {
        float v = dsp[k];
        v += __shfl_xor(v, 1);
        v += __shfl_xor(v, 2);
        v += __shfl_xor(v, 4);
        v += __shfl_xor(v, 8);
        dsp[k] = v;
    }
    if (l16 == 0) {
        #pragma unroll
        for (int a = 0; a < 2; ++a)
            #pragma unroll
            for (int r = 0; r < 4; ++r) {
                const int row = (w >> 1) * 32 + a * 16 + quad * 4 + r;
                dsred[w & 1][row] = dsp[a * 4 + r];
            }
    }
    __syncthreads();
    if (t < 64) out[(size_t)b * N_ + it0 + t] = dsred[0][t] + dsred[1][t];
}

extern "C" void kernel_launch(void* const* d_in, const int* in_sizes, int n_in,
                              void* d_out, int out_size, void* d_ws, size_t ws_size,
                              hipStream_t stream) {
    const float* val   = (const float*)d_in[0];
    const float* state = (const float*)d_in[1];
    float* out = (float*)d_out;

    const size_t nE         = (size_t)B_ * N_ * D_;                 // 4,194,304
    const size_t need_base  = 2 * nE * sizeof(unsigned short);      // 16.78 MB
    const size_t need_split = need_base + 2 * nE * sizeof(float)
                            + 2 * (size_t)B_ * N_ * sizeof(float);  // ~50.5 MB

    if (ws_size >= need_split) {
        unsigned short* Vb = (unsigned short*)d_ws;
        unsigned short* VF = Vb + nE;
        float* dvp = (float*)(VF + nE);          // [2][B*N*D]
        float* dsp = dvp + 2 * nE;               // [2][B*N]
        prepass_kernel<<<dim3(1024), dim3(256), 0, stream>>>(val, Vb, VF);
        prop_main<<<dim3(512), dim3(256), 0, stream>>>(state, Vb, VF, dvp, dsp);
        const int NDV4 = B_ * N_ * D_ / 4;
        const int NDS4 = B_ * N_ / 4;
        combine_kernel<<<dim3((NDV4 + NDS4) / 256), dim3(256), 0, stream>>>(
            (const float4*)dvp, (const float4*)(dvp + nE),
            dsp, dsp + (size_t)B_ * N_, out);
    } else {
        prop_kernel_fb<<<dim3(256), dim3(256), 0, stream>>>(val, state, out);
    }
}